// Round 7
// baseline (439.395 us; speedup 1.0000x reference)
//
#include <hip/hip_runtime.h>
#include <hip/hip_bf16.h>
#include <cstdint>
#include <cmath>

#define B_ 64
#define C_ 1280
#define S_ 256

typedef __attribute__((ext_vector_type(8))) short short8;
typedef __attribute__((ext_vector_type(4))) float f32x4;

typedef const __attribute__((address_space(1))) char gch;
typedef __attribute__((address_space(3))) char lch;

__device__ __forceinline__ void gload_lds16(const void* g, void* l) {
    __builtin_amdgcn_global_load_lds((gch*)g, (lch*)l, 16, 0, 0);
}

__device__ __forceinline__ unsigned short f2bu(float f) {
    __hip_bfloat16 h = __float2bfloat16(f);
    return *reinterpret_cast<unsigned short*>(&h);
}

// ============ prep_x: x-transpose (blocks 0..20479) + weight prep (20480..26879) ============
// x [B][C][S] fp32 -> xT [B*S][C] bf16 ; Wq/Wk/Wv -> transposed bf16 ; Wr -> bf16 copy
__global__ void prep_x(const float* __restrict__ x, __hip_bfloat16* __restrict__ xT,
                       const float* __restrict__ Wk, const float* __restrict__ Wq,
                       const float* __restrict__ Wv, const float* __restrict__ Wr,
                       __hip_bfloat16* __restrict__ WqT, __hip_bfloat16* __restrict__ WkT,
                       __hip_bfloat16* __restrict__ WvT, __hip_bfloat16* __restrict__ Wrb) {
    __shared__ float tile[32][33];
    int id = blockIdx.x;
    int tx = threadIdx.x, ty = threadIdx.y;
    if (id < 20480) {
        int b = id / 320;
        int rem = id - b * 320;
        int s0 = (rem & 7) * 32, c0 = (rem >> 3) * 32;
        const float* xb = x + (long)b * C_ * S_;
#pragma unroll
        for (int dy = 0; dy < 32; dy += 8)
            tile[ty + dy][tx] = xb[(long)(c0 + ty + dy) * S_ + s0 + tx];
        __syncthreads();
        __hip_bfloat16* xTb = xT + (long)b * S_ * C_;
#pragma unroll
        for (int dy = 0; dy < 32; dy += 8)
            xTb[(long)(s0 + ty + dy) * C_ + c0 + tx] = __float2bfloat16(tile[tx][ty + dy]);
    } else {
        int wid = id - 20480;
        int z = wid / 1600;
        int rem = wid - z * 1600;
        int r0 = (rem / 40) * 32, c0 = (rem - (rem / 40) * 40) * 32;
        const float* src = (z == 0) ? Wq : (z == 1) ? Wk : (z == 2) ? Wv : Wr;
        __hip_bfloat16* dst = (z == 0) ? WqT : (z == 1) ? WkT : (z == 2) ? WvT : Wrb;
        if (z == 3) {
#pragma unroll
            for (int dy = 0; dy < 32; dy += 8) {
                int idx = (r0 + ty + dy) * C_ + c0 + tx;
                dst[idx] = __float2bfloat16(src[idx]);
            }
            return;
        }
#pragma unroll
        for (int dy = 0; dy < 32; dy += 8)
            tile[ty + dy][tx] = src[(long)(r0 + ty + dy) * C_ + c0 + tx];
        __syncthreads();
#pragma unroll
        for (int dy = 0; dy < 32; dy += 8)
            dst[(long)(c0 + ty + dy) * C_ + r0 + tx] = __float2bfloat16(tile[tx][ty + dy]);
    }
}

// ---------------- softmax over batch axis ----------------
__global__ void softmax_b(const float* __restrict__ scores, __hip_bfloat16* __restrict__ Abf) {
    int tid = blockIdx.x * blockDim.x + threadIdx.x;  // 0..65535
    float r[64];
    float mx = -1e30f;
#pragma unroll
    for (int b = 0; b < 64; ++b) {
        r[b] = scores[(long)b * 65536 + tid];
        mx = fmaxf(mx, r[b]);
    }
    float sum = 0.f;
#pragma unroll
    for (int b = 0; b < 64; ++b) {
        r[b] = __expf(r[b] - mx);
        sum += r[b];
    }
    float inv = 1.0f / sum;
#pragma unroll
    for (int b = 0; b < 64; ++b)
        Abf[(long)b * 65536 + tid] = __float2bfloat16(r[b] * inv);
}

// ================= 8-phase 256x256 TN GEMM (BK=32, 512 thr, 8 waves 2x4) =================
// C[m][n] = sum_k A[m][k]*B[n][k].  tn < vTile -> bf16 row-major into Cc;
// tn >= vTile -> output written transposed to Vb[b(tm)][c][s] bf16 (the P projection).
// LDS: 8 slots x 8KB (64KB total -> 2 blocks/CU); slot(kt,j) = (kt&1)*4 + j;
// j: 0=A rows[0,128) 1=A rows[128,256) 2=B rows[0,128) 3=B rows[128,256).
// Half-tile: 128 rows x 32 bf16 (64B); swizzle byte(row,chunk) = row*64 + (chunk^(row&3))*16.
// Staging: linear LDS dest (t*16), inverse-swizzled global source; 1 load/thread/STAGE.
// Counted vmcnt: gates wait vmcnt(1) (retire 4 slots of the needed K-tile, carry 1).

#define PH_TOP()                                                \
    do {                                                        \
        __builtin_amdgcn_sched_barrier(0);                      \
        __builtin_amdgcn_s_barrier();                           \
        asm volatile("s_waitcnt lgkmcnt(0)" ::: "memory");      \
        __builtin_amdgcn_sched_barrier(0);                      \
        __builtin_amdgcn_s_setprio(1);                          \
    } while (0)

#define PH_BOT()                                                \
    do {                                                        \
        __builtin_amdgcn_s_setprio(0);                          \
        __builtin_amdgcn_sched_barrier(0);                      \
        __builtin_amdgcn_s_barrier();                           \
    } while (0)

#define PH_BOT_WAIT(LAST_)                                          \
    do {                                                            \
        __builtin_amdgcn_s_setprio(0);                              \
        __builtin_amdgcn_sched_barrier(0);                          \
        if (LAST_) asm volatile("s_waitcnt vmcnt(0)" ::: "memory"); \
        else       asm volatile("s_waitcnt vmcnt(1)" ::: "memory"); \
        __builtin_amdgcn_s_barrier();                               \
    } while (0)

#define MFMA_Q(MO, NO, BFV)                                                                        \
    _Pragma("unroll") for (int m = 0; m < 4; ++m) {                                                \
        _Pragma("unroll") for (int n = 0; n < 2; ++n) {                                            \
            acc[m + MO][n + NO] = __builtin_amdgcn_mfma_f32_16x16x32_bf16(                         \
                af[m], BFV[n], acc[m + MO][n + NO], 0, 0, 0);                                      \
        }                                                                                          \
    }

#define LOAD_A(SLOT, RO)                                  \
    _Pragma("unroll") for (int m = 0; m < 4; ++m) {       \
        af[m] = RD(SLOT, (RO) + m * 16 + l15);            \
    }

#define LOAD_B(SLOT, BFV, NO)                             \
    _Pragma("unroll") for (int n = 0; n < 2; ++n) {       \
        BFV[n] = RD(SLOT, rB0 + ((NO) + n) * 16 + l15);   \
    }

__global__ __launch_bounds__(512, 2) void gemm8p(
    const __hip_bfloat16* __restrict__ A, const __hip_bfloat16* __restrict__ Bm,
    __hip_bfloat16* __restrict__ Cc, int lda, int ldb, int ldc,
    int Kd, int tilesN, int nwg, int vTile,
    __hip_bfloat16* __restrict__ Vb) {
    __shared__ char lds[65536];

    int bid = blockIdx.x;
    int cpx = nwg >> 3;
    int swz = (bid & 7) * cpx + (bid >> 3);
    int tm = swz / tilesN, tn = swz - tm * tilesN;

    int t = threadIdx.x;
    int lane = t & 63, w = t >> 6;
    int wm = w >> 2, wn = w & 3;
    int l15 = lane & 15, lhi = lane >> 4;
    int rB0 = (wn & 1) * 64;
    const int sA0 = wm, sB0 = 2 + (wn >> 1);
    const int sA1 = 4 + wm, sB1 = 6 + (wn >> 1);

    const __hip_bfloat16* aT = A + (long)tm * 256 * lda;
    const __hip_bfloat16* bT = Bm + (long)tn * 256 * ldb;

    int srow = t >> 2;                    // 0..127
    int sc = ((t & 3) ^ (srow & 3)) * 8;  // inverse-swizzled k-chunk (elements)
    const __hip_bfloat16* stA = aT + (long)srow * lda + sc;
    const __hip_bfloat16* stB = bT + (long)srow * ldb + sc;

    auto STAGE = [&](int kt, int j) {
        const __hip_bfloat16* p;
        if (j < 2) p = stA + (long)j * 128 * lda + kt * 32;
        else       p = stB + (long)(j - 2) * 128 * ldb + kt * 32;
        char* slot = lds + (((kt & 1) * 4 + j) << 13);
        gload_lds16(p, slot + t * 16);
    };

    auto RD = [&](int slotIdx, int row) -> short8 {
        const char* p = lds + (slotIdx << 13) + row * 64 +
                        ((lhi ^ (row & 3)) << 4);
        return *reinterpret_cast<const short8*>(p);
    };

    f32x4 acc[8][4];
#pragma unroll
    for (int i = 0; i < 8; ++i)
#pragma unroll
        for (int j = 0; j < 4; ++j) acc[i][j] = (f32x4){0.f, 0.f, 0.f, 0.f};

    short8 af[4], b0v[2], b1v[2];

    // prologue: K-tile 0 (4 slots) + (1, slot0); retire K-tile 0, carry 1
    STAGE(0, 0); STAGE(0, 1); STAGE(0, 2); STAGE(0, 3); STAGE(1, 0);
    asm volatile("s_waitcnt vmcnt(1)" ::: "memory");
    __builtin_amdgcn_s_barrier();
    __builtin_amdgcn_sched_barrier(0);

    const int NTH = Kd >> 6;  // iterations; 2 K-tiles (of 32) each
    for (int i = 0; i < NTH; ++i) {
        const bool last = (i == NTH - 1);
        const int kt0 = 2 * i, kt1 = 2 * i + 1;

        // phase 0: kt0 q0 (m 0-3 x n 0-1)
        LOAD_A(sA0, 0)
        LOAD_B(sB0, b0v, 0)
        STAGE(kt1, 1);
        PH_TOP();
        MFMA_Q(0, 0, b0v)
        PH_BOT();

        // phase 1: kt0 q1 (m 0-3 x n 2-3)
        LOAD_B(sB0, b1v, 2)
        STAGE(kt1, 2);
        PH_TOP();
        MFMA_Q(0, 2, b1v)
        PH_BOT();

        // phase 2: kt0 q2 (m 4-7 x n 2-3)
        LOAD_A(sA0, 64)
        STAGE(kt1, 3);
        PH_TOP();
        MFMA_Q(4, 2, b1v)
        PH_BOT();

        // phase 3: kt0 q3 (m 4-7 x n 0-1); gate K-tile kt1
        if (!last) STAGE(kt0 + 2, 0);
        PH_TOP();
        MFMA_Q(4, 0, b0v)
        PH_BOT_WAIT(last);

        // phase 4: kt1 q0
        LOAD_A(sA1, 0)
        LOAD_B(sB1, b0v, 0)
        if (!last) STAGE(kt0 + 2, 1);
        PH_TOP();
        MFMA_Q(0, 0, b0v)
        PH_BOT();

        // phase 5: kt1 q1
        LOAD_B(sB1, b1v, 2)
        if (!last) STAGE(kt0 + 2, 2);
        PH_TOP();
        MFMA_Q(0, 2, b1v)
        PH_BOT();

        // phase 6: kt1 q2
        LOAD_A(sA1, 64)
        if (!last) STAGE(kt0 + 2, 3);
        PH_TOP();
        MFMA_Q(4, 2, b1v)
        PH_BOT();

        // phase 7: kt1 q3; gate K-tile kt0+2
        if (!last) STAGE(kt0 + 3, 0);
        PH_TOP();
        MFMA_Q(4, 0, b0v)
        __builtin_amdgcn_s_setprio(0);
        __builtin_amdgcn_sched_barrier(0);
        if (!last) asm volatile("s_waitcnt vmcnt(1)" ::: "memory");
        __builtin_amdgcn_s_barrier();
    }

    // epilogue: D frag (m,n): col = l15 (B-row), row = lhi*4 + r (A-row)
    if (tn < vTile) {
        long crow0 = (long)tm * 256 + wm * 128;
        int cc0 = tn * 256 + wn * 64;
#pragma unroll
        for (int m = 0; m < 8; ++m) {
            long gm = crow0 + m * 16 + lhi * 4;
#pragma unroll
            for (int n = 0; n < 4; ++n) {
                int gn = cc0 + n * 16 + l15;
#pragma unroll
                for (int r = 0; r < 4; ++r)
                    Cc[(gm + r) * ldc + gn] = __float2bfloat16(acc[m][n][r]);
            }
        }
    } else {
        // P region: write transposed to Vb[b][c][s], b = tm
        unsigned short* Vus = (unsigned short*)Vb;
        int cb0 = (tn - vTile) * 256 + wn * 64;
#pragma unroll
        for (int m = 0; m < 8; ++m) {
            int s0 = wm * 128 + m * 16 + lhi * 4;
#pragma unroll
            for (int n = 0; n < 4; ++n) {
                int c = cb0 + n * 16 + l15;
                ushort4 pk;
                pk.x = f2bu(acc[m][n][0]);
                pk.y = f2bu(acc[m][n][1]);
                pk.z = f2bu(acc[m][n][2]);
                pk.w = f2bu(acc[m][n][3]);
                *reinterpret_cast<ushort4*>(&Vus[((long)(tm * 1280 + c) << 8) + s0]) = pk;
            }
        }
    }
}

// ====== gemm_scores: prefetched dbuf 128x128, swizzled [128][32] tiles ======
// scores[b][i][j] = scale * sum_c G[b,i,c] * xT[b,j,c]; grid 256 = b*4 + tm*2 + tn
__global__ __launch_bounds__(256) void gemm_scores(
    const __hip_bfloat16* __restrict__ G, const __hip_bfloat16* __restrict__ xT,
    float* __restrict__ scores, float scale) {
    __shared__ __hip_bfloat16 lA[2][4096];
    __shared__ __hip_bfloat16 lB[2][4096];

    int blk = blockIdx.x;
    int b = blk >> 2, tm = (blk >> 1) & 1, tn = blk & 1;
    int t = threadIdx.x, lane = t & 63, w = t >> 6;
    int wm = w >> 1, wn = w & 1;
    int l15 = lane & 15, lhi = lane >> 4;
    int kx = (lhi ^ (l15 & 3)) << 4;  // lane-constant swizzled chunk byte offset

    const __hip_bfloat16* Ab = G + (long)b * (S_ * C_) + (long)tm * 128 * C_;
    const __hip_bfloat16* Bb = xT + (long)b * (S_ * C_) + (long)tn * 128 * C_;

    int arow = t >> 2;
    int acol = ((t & 3) ^ (arow & 3)) * 8;  // inverse-swizzled source chunk

    auto STAGE = [&](int k0, int buf) {
        gload_lds16(Ab + (long)arow * C_ + k0 + acol, (char*)lA[buf] + t * 16);
        gload_lds16(Ab + (long)(arow + 64) * C_ + k0 + acol, (char*)lA[buf] + t * 16 + 4096);
        gload_lds16(Bb + (long)arow * C_ + k0 + acol, (char*)lB[buf] + t * 16);
        gload_lds16(Bb + (long)(arow + 64) * C_ + k0 + acol, (char*)lB[buf] + t * 16 + 4096);
    };

    f32x4 acc[4][4];
#pragma unroll
    for (int i = 0; i < 4; ++i)
#pragma unroll
        for (int j = 0; j < 4; ++j) acc[i][j] = (f32x4){0.f, 0.f, 0.f, 0.f};

    STAGE(0, 0);
    __syncthreads();

#pragma unroll 2
    for (int k = 0; k < 40; ++k) {
        int cur = k & 1;
        if (k < 39) STAGE((k + 1) * 32, cur ^ 1);
        short8 af[4], bf[4];
#pragma unroll
        for (int i = 0; i < 4; ++i)
            af[i] = *reinterpret_cast<const short8*>(
                (const char*)lA[cur] + (wm * 64 + i * 16 + l15) * 64 + kx);
#pragma unroll
        for (int j = 0; j < 4; ++j)
            bf[j] = *reinterpret_cast<const short8*>(
                (const char*)lB[cur] + (wn * 64 + j * 16 + l15) * 64 + kx);
#pragma unroll
        for (int i = 0; i < 4; ++i)
#pragma unroll
            for (int j = 0; j < 4; ++j)
                acc[i][j] = __builtin_amdgcn_mfma_f32_16x16x32_bf16(af[i], bf[j], acc[i][j], 0, 0, 0);
        __syncthreads();
    }

    float* Cb = scores + (long)b * 65536;
#pragma unroll
    for (int i = 0; i < 4; ++i) {
        int gm = tm * 128 + wm * 64 + i * 16 + lhi * 4;
#pragma unroll
        for (int j = 0; j < 4; ++j) {
            int gn = tn * 128 + wn * 64 + j * 16 + l15;
#pragma unroll
            for (int r = 0; r < 4; ++r)
                Cb[(long)(gm + r) * 256 + gn] = acc[i][j][r] * scale;
        }
    }
}

// ====== gemm_weights: two 1280^3 TN GEMMs, prefetched dbuf, one dispatch (200 blocks) ======
// blk<100: Bcat[0..1280) = scale * WqT x WkT ; blk>=100: Bcat[1280..2560) = Wrb x WvT
__global__ __launch_bounds__(256) void gemm_weights(
    const __hip_bfloat16* __restrict__ WqT, const __hip_bfloat16* __restrict__ WkT,
    const __hip_bfloat16* __restrict__ Wrb, const __hip_bfloat16* __restrict__ WvT,
    __hip_bfloat16* __restrict__ Bcat, float scale) {
    __shared__ __hip_bfloat16 lA[2][4096];
    __shared__ __hip_bfloat16 lB[2][4096];

    int blk = blockIdx.x;
    const __hip_bfloat16 *A, *Bm;
    __hip_bfloat16* Cb;
    float sc;
    int rem;
    if (blk < 100) { A = WqT; Bm = WkT; Cb = Bcat; sc = scale; rem = blk; }
    else { A = Wrb; Bm = WvT; Cb = Bcat + 1280 * 1280; sc = 1.f; rem = blk - 100; }
    int tm = rem / 10, tn = rem - tm * 10;

    int t = threadIdx.x, lane = t & 63, w = t >> 6;
    int wm = w >> 1, wn = w & 1;
    int l15 = lane & 15, lhi = lane >> 4;
    int kx = (lhi ^ (l15 & 3)) << 4;

    const __hip_bfloat16* Ab = A + (long)tm * 128 * C_;
    const __hip_bfloat16* Bb = Bm + (long)tn * 128 * C_;

    int arow = t >> 2;
    int acol = ((t & 3) ^ (arow & 3)) * 8;

    auto STAGE = [&](int k0, int buf) {
        gload_lds16(Ab + (long)arow * C_ + k0 + acol, (char*)lA[buf] + t * 16);
        gload_lds16(Ab + (long)(arow + 64) * C_ + k0 + acol, (char*)lA[buf] + t * 16 + 4096);
        gload_lds16(Bb + (long)arow * C_ + k0 + acol, (char*)lB[buf] + t * 16);
        gload_lds16(Bb + (long)(arow + 64) * C_ + k0 + acol, (char*)lB[buf] + t * 16 + 4096);
    };

    f32x4 acc[4][4];
#pragma unroll
    for (int i = 0; i < 4; ++i)
#pragma unroll
        for (int j = 0; j < 4; ++j) acc[i][j] = (f32x4){0.f, 0.f, 0.f, 0.f};

    STAGE(0, 0);
    __syncthreads();

#pragma unroll 2
    for (int k = 0; k < 40; ++k) {
        int cur = k & 1;
        if (k < 39) STAGE((k + 1) * 32, cur ^ 1);
        short8 af[4], bf[4];
#pragma unroll
        for (int i = 0; i < 4; ++i)
            af[i] = *reinterpret_cast<const short8*>(
                (const char*)lA[cur] + (wm * 64 + i * 16 + l15) * 64 + kx);
#pragma unroll
        for (int j = 0; j < 4; ++j)
            bf[j] = *reinterpret_cast<const short8*>(
                (const char*)lB[cur] + (wn * 64 + j * 16 + l15) * 64 + kx);
#pragma unroll
        for (int i = 0; i < 4; ++i)
#pragma unroll
            for (int j = 0; j < 4; ++j)
                acc[i][j] = __builtin_amdgcn_mfma_f32_16x16x32_bf16(af[i], bf[j], acc[i][j], 0, 0, 0);
        __syncthreads();
    }

#pragma unroll
    for (int i = 0; i < 4; ++i) {
        int gm = tm * 128 + wm * 64 + i * 16 + lhi * 4;
#pragma unroll
        for (int j = 0; j < 4; ++j) {
            int gn = tn * 128 + wn * 64 + j * 16 + l15;
#pragma unroll
            for (int r = 0; r < 4; ++r)
                Cb[(long)(gm + r) * C_ + gn] = __float2bfloat16(acc[i][j][r] * sc);
        }
    }
}

// ====== final_att2: out[b][c][s] = alpha * sum_j Abf[b,s,j]*P[b,c,j] + x[b][c][s] ======
// 128(s) x 256(c) tiles, prefetched dbuf, swizzled. Grid 640 = b*10 + tm*5 + tnp.
__global__ __launch_bounds__(256, 2) void final_att2(
    const __hip_bfloat16* __restrict__ Abf, const __hip_bfloat16* __restrict__ P,
    const float* __restrict__ x, const float* __restrict__ alphaPtr,
    float* __restrict__ out) {
    __shared__ __hip_bfloat16 lA[2][4096];  // 128 x 32
    __shared__ __hip_bfloat16 lB[2][8192];  // 256 x 32

    int blk = blockIdx.x;
    int b = blk / 10;
    int rem = blk - b * 10;
    int tm = rem / 5, tnp = rem - tm * 5;

    int t = threadIdx.x, lane = t & 63, w = t >> 6;
    int wm = w >> 1, wn = w & 1;
    int l15 = lane & 15, lhi = lane >> 4;
    int kx = (lhi ^ (l15 & 3)) << 4;

    const __hip_bfloat16* Ab = Abf + (long)b * 65536 + (long)tm * 128 * 256;
    const __hip_bfloat16* Bb = P + (long)b * (C_ * S_) + (long)tnp * 256 * 256;

    int arow = t >> 2;
    int acol = ((t & 3) ^ (arow & 3)) * 8;

    auto STAGE = [&](int k0, int buf) {
        gload_lds16(Ab + (long)arow * 256 + k0 + acol, (char*)lA[buf] + t * 16);
        gload_lds16(Ab + (long)(arow + 64) * 256 + k0 + acol, (char*)lA[buf] + t * 16 + 4096);
#pragma unroll
        for (int j = 0; j < 4; ++j)
            gload_lds16(Bb + (long)(arow + j * 64) * 256 + k0 + acol,
                        (char*)lB[buf] + t * 16 + j * 4096);
    };

    f32x4 acc[4][8];
#pragma unroll
    for (int i = 0; i < 4; ++i)
#pragma unroll
        for (int n = 0; n < 8; ++n) acc[i][n] = (f32x4){0.f, 0.f, 0.f, 0.f};

    STAGE(0, 0);
    __syncthreads();

#pragma unroll
    for (int k = 0; k < 8; ++k) {
        int cur = k & 1;
        if (k < 7) STAGE((k + 1) * 32, cur ^ 1);
        short8 af[4], bf[8];
#pragma unroll
        for (int i = 0; i < 4; ++i)
            af[i] = *reinterpret_cast<const short8*>(
                (const char*)lA[cur] + (wm * 64 + i * 16 + l15) * 64 + kx);
#pragma unroll
        for (int n = 0; n < 8; ++n)
            bf[n] = *reinterpret_cast<const short8*>(
                (const char*)lB[cur] + (wn * 128 + n * 16 + l15) * 64 + kx);
#pragma unroll
        for (int i = 0; i < 4; ++i)
#pragma unroll
            for (int n = 0; n < 8; ++n)
                acc[i][n] = __builtin_amdgcn_mfma_f32_16x16x32_bf16(af[i], bf[n], acc[i][n], 0, 0, 0);
        __syncthreads();
    }

    float alpha = alphaPtr[0];
    long bOff = (long)b * (C_ * S_);
#pragma unroll
    for (int i = 0; i < 4; ++i) {
        int s0 = tm * 128 + wm * 64 + i * 16 + lhi * 4;
#pragma unroll
        for (int n = 0; n < 8; ++n) {
            int c = tnp * 256 + wn * 128 + n * 16 + l15;
            long base = bOff + (long)c * 256 + s0;
            f32x4 xv = *reinterpret_cast<const f32x4*>(x + base);
            f32x4 o;
#pragma unroll
            for (int r = 0; r < 4; ++r) o[r] = alpha * acc[i][n][r] + xv[r];
            *reinterpret_cast<f32x4*>(out + base) = o;
        }
    }
}

extern "C" void kernel_launch(void* const* d_in, const int* in_sizes, int n_in,
                              void* d_out, int out_size, void* d_ws, size_t ws_size,
                              hipStream_t stream) {
    const float* x = (const float*)d_in[0];
    const float* Wk = (const float*)d_in[1];
    const float* Wq = (const float*)d_in[2];
    const float* Wv = (const float*)d_in[3];
    const float* Wr = (const float*)d_in[4];
    const float* alphaPtr = (const float*)d_in[5];

    char* ws = (char*)d_ws;
    size_t off = 0;
    auto alloc = [&](size_t bytes) {
        char* p = ws + off;
        off += (bytes + 255) & ~(size_t)255;
        return p;
    };
    const size_t BSC = (size_t)B_ * S_ * C_;  // 16384*1280
    const size_t CC = (size_t)C_ * C_;

    __hip_bfloat16* xT = (__hip_bfloat16*)alloc(BSC * 2);  // [16384][1280]
    __hip_bfloat16* WqT = (__hip_bfloat16*)alloc(CC * 2);
    __hip_bfloat16* WkT = (__hip_bfloat16*)alloc(CC * 2);
    __hip_bfloat16* WvT = (__hip_bfloat16*)alloc(CC * 2);
    __hip_bfloat16* Wrb = (__hip_bfloat16*)alloc(CC * 2);
    __hip_bfloat16* Bcat = (__hip_bfloat16*)alloc(2 * CC * 2);  // [2560][1280]: Bproj ; Wrv
    __hip_bfloat16* G = (__hip_bfloat16*)alloc(BSC * 2);        // [16384][1280]
    __hip_bfloat16* P = (__hip_bfloat16*)alloc(BSC * 2);        // [B][C][S]
    float* scores = (float*)alloc((size_t)B_ * S_ * S_ * 4);
    __hip_bfloat16* Abf = (__hip_bfloat16*)alloc((size_t)B_ * S_ * S_ * 2);

    const float scale = 1.0f / sqrtf((float)C_);

    // 1) x -> xT bf16 + weight transposes (one dispatch)
    prep_x<<<26880, dim3(32, 8), 0, stream>>>(x, xT, Wk, Wq, Wv, Wr, WqT, WkT, WvT, Wrb);

    // 2) Bcat = [ scale*(Wq^T Wk) ; Wr*Wv ]
    gemm_weights<<<200, 256, 0, stream>>>(WqT, WkT, Wrb, WvT, Bcat, scale);

    // 3) projections: G = xT * Bproj^T (row-major), P = xT * Wrv^T (transposed to [B][C][S])
    gemm8p<<<640, 512, 0, stream>>>(xT, Bcat, G, C_, C_, C_, C_, 10, 640, 5, P);

    // 4) scores[b][i][j] = sum_c G[b,i,c] * xT[b,j,c]  (scale folded into Bproj)
    gemm_scores<<<256, 256, 0, stream>>>(G, xT, scores, 1.0f);

    // 5) softmax over batch axis
    softmax_b<<<256, 256, 0, stream>>>(scores, Abf);

    // 6) out[b][c][s] = alpha * sum_j A[b,s,j] P[b,c,j] + x[b][c][s]
    final_att2<<<640, 256, 0, stream>>>(Abf, P, x, alphaPtr, (float*)d_out);
}